// Round 3
// baseline (2877.038 us; speedup 1.0000x reference)
//
#include <hip/hip_runtime.h>

#define DIV_UP(a,b) (((a)+(b)-1)/(b))

// ---------- ordered-uint float max keys ----------
__device__ __forceinline__ unsigned f2key(float f) {
  unsigned u = __float_as_uint(f);
  return (u & 0x80000000u) ? ~u : (u | 0x80000000u);
}
__device__ __forceinline__ float key2f(unsigned u) {
  unsigned b = (u & 0x80000000u) ? (u ^ 0x80000000u) : ~u;
  return __uint_as_float(b);
}

// ---------- utility ----------
__global__ void k_zero(int* p, int n) {
  int i = blockIdx.x * blockDim.x + threadIdx.x;
  if (i < n) p[i] = 0;
}

// ---------- degree count ----------
__global__ void k_count(const int* __restrict__ row, int* __restrict__ cnt, int E) {
  int e = blockIdx.x * blockDim.x + threadIdx.x;
  if (e < E) atomicAdd(&cnt[row[e]], 1);
}

__global__ void k_dis(const int* __restrict__ cnt, float* __restrict__ dis, int N) {
  int i = blockIdx.x * blockDim.x + threadIdx.x;
  if (i < N) {
    int c = cnt[i];
    dis[i] = (c > 0) ? rsqrtf((float)c) : 0.0f;
  }
}

// ---------- 3-kernel exclusive scan over cnt -> rowptr ----------
__global__ void k_scan1(const int* __restrict__ cnt, int* __restrict__ incl,
                        int* __restrict__ bsum, int N) {
  __shared__ int s[1024];
  int t = threadIdx.x;
  int i = blockIdx.x * 1024 + t;
  int v = (i < N) ? cnt[i] : 0;
  s[t] = v;
  __syncthreads();
  for (int off = 1; off < 1024; off <<= 1) {
    int add = (t >= off) ? s[t - off] : 0;
    __syncthreads();
    s[t] += add;
    __syncthreads();
  }
  if (i < N) incl[i] = s[t];
  if (t == 1023) bsum[blockIdx.x] = s[1023];
}

__global__ void k_scan2(const int* __restrict__ bsum, int* __restrict__ bex, int nb) {
  if (threadIdx.x == 0) {
    int run = 0;
    for (int b = 0; b < nb; ++b) { bex[b] = run; run += bsum[b]; }
  }
}

__global__ void k_scan3(const int* __restrict__ incl, const int* __restrict__ cnt,
                        const int* __restrict__ bex, int* __restrict__ rowptr,
                        int* __restrict__ cursor, int N, int E) {
  int i = blockIdx.x * blockDim.x + threadIdx.x;
  if (i < N) {
    int v = incl[i] - cnt[i] + bex[i >> 10];
    rowptr[i] = v;
    cursor[i] = v;
  }
  if (i == 0) rowptr[N] = E;
}

// ---------- CSR fill ----------
__global__ void k_fill(const int* __restrict__ row, const int* __restrict__ col,
                       const float* __restrict__ dis, int* __restrict__ cursor,
                       int* __restrict__ csr_col, float* __restrict__ csr_w, int E) {
  int e = blockIdx.x * blockDim.x + threadIdx.x;
  if (e >= E) return;
  int r = row[e], c = col[e];
  int idx = atomicAdd(&cursor[r], 1);
  csr_col[idx] = c;
  csr_w[idx] = -dis[r] * dis[c];
}

// ---------- prop: one wave per row, lane = feature, 8-wide MLP ----------
template <bool CHEB2>
__global__ __launch_bounds__(256) void k_prop(const int* __restrict__ rowptr,
                                              const int* __restrict__ csr_col,
                                              const float* __restrict__ csr_w,
                                              const float* __restrict__ z,
                                              const float* __restrict__ tx0,
                                              float* __restrict__ out, int N) {
  int n = blockIdx.x * 4 + (threadIdx.x >> 6);
  int lane = threadIdx.x & 63;
  if (n >= N) return;
  int beg = rowptr[n], end = rowptr[n + 1];
  float acc = 0.0f;
  for (int j = beg; j < end; j += 8) {
    int cc[8];
    float ww[8];
#pragma unroll
    for (int u = 0; u < 8; ++u) {
      int jj = j + u;
      bool ok = jj < end;          // wave-uniform
      cc[u] = ok ? csr_col[jj] : 0;
      ww[u] = ok ? csr_w[jj] : 0.0f;
    }
    float vv[8];
#pragma unroll
    for (int u = 0; u < 8; ++u) vv[u] = z[(size_t)cc[u] * 64 + lane];
#pragma unroll
    for (int u = 0; u < 8; ++u) acc = fmaf(ww[u], vv[u], acc);
  }
  if (CHEB2)
    out[(size_t)n * 64 + lane] = 2.0f * acc - tx0[(size_t)n * 64 + lane];
  else
    out[(size_t)n * 64 + lane] = acc;
}

// ---------- GEMM v3: lane=row, 16 cols/lane, W via LDS broadcast ----------
// block = 256 threads = 4 waves; block computes rows [64*bid,64*bid+64) x 64 cols.
// Wave w handles cols [16w,16w+16). x read directly from global (float4,
// L1-shared across the 4 waves); W staged once to LDS, read as wave-uniform
// broadcast ds_read_b128 (conflict-free). 64 FMAs per x-load -> VALU-bound.
template <int KK, bool ACC, bool STATS>
__global__ __launch_bounds__(256) void k_gemm_v3(const float* __restrict__ t0,
                                                 const float* __restrict__ t1,
                                                 const float* __restrict__ t2,
                                                 const float* __restrict__ W,
                                                 const float* __restrict__ bias,
                                                 float* __restrict__ out,
                                                 float* __restrict__ sums,
                                                 float* __restrict__ sumsq, int N) {
  __shared__ float w_s[KK * 64 * 64];
  __shared__ float b_s[64];
  for (int i = threadIdx.x * 4; i < KK * 4096; i += 1024)
    *(float4*)&w_s[i] = *(const float4*)&W[i];
  if (threadIdx.x < 64) b_s[threadIdx.x] = bias[threadIdx.x];
  __syncthreads();

  int lane = threadIdx.x & 63;
  int h0 = (threadIdx.x >> 6) << 4;  // wave-uniform: 0,16,32,48
  int row = blockIdx.x * 64 + lane;
  bool valid = row < N;
  const float* ts[3] = {t0, t1, t2};

  float acc[16];
#pragma unroll
  for (int h = 0; h < 16; ++h) acc[h] = b_s[h0 + h];

#pragma unroll
  for (int k = 0; k < KK; ++k) {
    const float4* xp = (const float4*)(ts[k] + (size_t)row * 64);
#pragma unroll 4
    for (int d4 = 0; d4 < 16; ++d4) {
      float4 xv = valid ? xp[d4] : make_float4(0.f, 0.f, 0.f, 0.f);
#pragma unroll
      for (int j = 0; j < 4; ++j) {
        float xs = (j == 0) ? xv.x : (j == 1) ? xv.y : (j == 2) ? xv.z : xv.w;
        const float* wr = &w_s[(k * 64 + d4 * 4 + j) * 64 + h0];
#pragma unroll
        for (int q = 0; q < 4; ++q) {
          float4 wv = *(const float4*)&wr[q * 4];  // same addr all lanes -> broadcast
          acc[4 * q + 0] = fmaf(xs, wv.x, acc[4 * q + 0]);
          acc[4 * q + 1] = fmaf(xs, wv.y, acc[4 * q + 1]);
          acc[4 * q + 2] = fmaf(xs, wv.z, acc[4 * q + 2]);
          acc[4 * q + 3] = fmaf(xs, wv.w, acc[4 * q + 3]);
        }
      }
    }
  }

  if (STATS) {
#pragma unroll
    for (int h = 0; h < 16; ++h) {
      float v = valid ? acc[h] : 0.0f;
      float v2 = v * v;
#pragma unroll
      for (int off = 32; off > 0; off >>= 1) {
        v += __shfl_down(v, off, 64);
        v2 += __shfl_down(v2, off, 64);
      }
      if (lane == 0) {
        atomicAdd(&sums[h0 + h], v);
        atomicAdd(&sumsq[h0 + h], v2);
      }
    }
  }

  if (valid) {
    float* op = out + (size_t)row * 64 + h0;
#pragma unroll
    for (int q = 0; q < 4; ++q) {
      float4 v = make_float4(acc[4 * q], acc[4 * q + 1], acc[4 * q + 2], acc[4 * q + 3]);
      if (ACC) {
        float4 cur = ((float4*)op)[q];
        v.x += cur.x; v.y += cur.y; v.z += cur.z; v.w += cur.w;
      }
      ((float4*)op)[q] = v;
    }
  }
}

__global__ void k_bncoef(const float* __restrict__ sums, const float* __restrict__ sumsq,
                         const float* __restrict__ g, const float* __restrict__ be,
                         float* __restrict__ scale, float* __restrict__ shift, int N) {
  int h = threadIdx.x;
  if (h >= 64) return;
  float inv_n = 1.0f / (float)N;
  float mu = sums[h] * inv_n;
  float var = sumsq[h] * inv_n - mu * mu;
  float sc = g[h] * rsqrtf(var + 1e-5f);
  scale[h] = sc;
  shift[h] = be[h] - mu * sc;
}

// ---------- BN apply + LeakyReLU (float4) ----------
__global__ void k_bnapply(const float* __restrict__ X, const float* __restrict__ scale,
                          const float* __restrict__ shift, float* __restrict__ Y,
                          int total4) {
  int i = blockIdx.x * blockDim.x + threadIdx.x;
  if (i >= total4) return;
  int h = (i * 4) & 63;
  float4 v = ((const float4*)X)[i];
  float a, b, c, d;
  a = v.x * scale[h + 0] + shift[h + 0];
  b = v.y * scale[h + 1] + shift[h + 1];
  c = v.z * scale[h + 2] + shift[h + 2];
  d = v.w * scale[h + 3] + shift[h + 3];
  v.x = (a > 0.0f) ? a : 0.01f * a;
  v.y = (b > 0.0f) ? b : 0.01f * b;
  v.z = (c > 0.0f) ? c : 0.01f * c;
  v.w = (d > 0.0f) ? d : 0.01f * d;
  ((float4*)Y)[i] = v;
}

// ---------- pooling ----------
__global__ void k_poolinit(unsigned* __restrict__ pooled, int n) {
  int i = blockIdx.x * blockDim.x + threadIdx.x;
  if (i < n) pooled[i] = 0x007FFFFFu;  // key(-inf)
}

__global__ void k_pool(const float* __restrict__ X, const int* __restrict__ batch,
                       unsigned* __restrict__ pooled, int N) {
  int t = threadIdx.x;
  int h = t & 63;
  int rsub = t >> 6;
  int base = blockIdx.x * 64;
  int cur_g = -1;
  unsigned best = 0;
  for (int i = 0; i < 16; ++i) {
    int n = base + rsub + 4 * i;
    if (n >= N) break;
    int g = batch[n];
    unsigned k = f2key(X[(size_t)n * 64 + h]);
    if (g != cur_g) {
      if (cur_g >= 0) atomicMax(&pooled[cur_g * 64 + h], best);
      cur_g = g;
      best = k;
    } else {
      best = max(best, k);
    }
  }
  if (cur_g >= 0) atomicMax(&pooled[cur_g * 64 + h], best);
}

__global__ void k_final(const unsigned* __restrict__ pooled, const float* __restrict__ w_lin,
                        const float* __restrict__ b_lin, float* __restrict__ out) {
  int g = blockIdx.x;
  int h = threadIdx.x;
  float v = key2f(pooled[g * 64 + h]) * w_lin[h];
  for (int off = 32; off > 0; off >>= 1) v += __shfl_down(v, off, 64);
  if (h == 0) out[g] = v + b_lin[0];
}

extern "C" void kernel_launch(void* const* d_in, const int* in_sizes, int n_in,
                              void* d_out, int out_size, void* d_ws, size_t ws_size,
                              hipStream_t stream) {
  const float* x = (const float*)d_in[0];
  const int* ei = (const int*)d_in[1];
  const int* batch = (const int*)d_in[2];
  const float* w1 = (const float*)d_in[3];
  const float* b1 = (const float*)d_in[4];
  const float* w2 = (const float*)d_in[5];
  const float* b2 = (const float*)d_in[6];
  const float* w3 = (const float*)d_in[7];
  const float* b3 = (const float*)d_in[8];
  const float* g1 = (const float*)d_in[9];
  const float* be1 = (const float*)d_in[10];
  const float* g2 = (const float*)d_in[11];
  const float* be2 = (const float*)d_in[12];
  const float* g3 = (const float*)d_in[13];
  const float* be3 = (const float*)d_in[14];
  const float* w_sc = (const float*)d_in[15];
  const float* b_sc = (const float*)d_in[16];
  const float* w_lin = (const float*)d_in[17];
  const float* b_lin = (const float*)d_in[18];

  int N = in_sizes[0] / 64;
  int E = in_sizes[1] / 2;
  int G = out_size;
  const int* row = ei;
  const int* col = ei + E;

  char* p = (char*)d_ws;
  auto carve = [&](size_t bytes) -> void* {
    void* r = (void*)p;
    p += (bytes + 255) & ~(size_t)255;
    return r;
  };
  int* cnt = (int*)carve((size_t)N * 4);
  float* dis = (float*)carve((size_t)N * 4);
  int* rowptr = (int*)carve((size_t)(N + 1) * 4);
  int* cursor = (int*)carve((size_t)N * 4);
  int* incl = (int*)carve((size_t)N * 4);
  int* bsum = (int*)carve(1024);
  int* bex = (int*)carve(1024);
  int* csr_col = (int*)carve((size_t)E * 4);
  float* csr_w = (float*)carve((size_t)E * 4);
  float* A = (float*)carve((size_t)N * 64 * 4);
  float* B = (float*)carve((size_t)N * 64 * 4);
  float* C = (float*)carve((size_t)N * 64 * 4);
  float* Dh = (float*)carve((size_t)N * 64 * 4);
  float* stats = (float*)carve(256 * 4);  // sums|sumsq|scale|shift
  unsigned* pooled = (unsigned*)carve((size_t)G * 64 * 4);

  // ---- graph structure ----
  k_zero<<<DIV_UP(N, 256), 256, 0, stream>>>(cnt, N);
  k_count<<<DIV_UP(E, 256), 256, 0, stream>>>(row, cnt, E);
  k_dis<<<DIV_UP(N, 256), 256, 0, stream>>>(cnt, dis, N);
  int nb = DIV_UP(N, 1024);
  k_scan1<<<nb, 1024, 0, stream>>>(cnt, incl, bsum, N);
  k_scan2<<<1, 64, 0, stream>>>(bsum, bex, nb);
  k_scan3<<<DIV_UP(N, 256), 256, 0, stream>>>(incl, cnt, bex, rowptr, cursor, N, E);
  k_fill<<<DIV_UP(E, 256), 256, 0, stream>>>(row, col, dis, cursor, csr_col, csr_w, E);

  const float* Ws[3] = {w1, w2, w3};
  const float* bs[3] = {b1, b2, b3};
  const float* gs[3] = {g1, g2, g3};
  const float* bes[3] = {be1, be2, be3};

  int NB = DIV_UP(N, 64);
  const float* tx0 = x;
  for (int l = 0; l < 3; ++l) {
    k_prop<false><<<DIV_UP(N, 4), 256, 0, stream>>>(rowptr, csr_col, csr_w, tx0, nullptr, A, N);
    k_prop<true><<<DIV_UP(N, 4), 256, 0, stream>>>(rowptr, csr_col, csr_w, A, tx0, B, N);
    k_zero<<<1, 256, 0, stream>>>((int*)stats, 128);
    k_gemm_v3<3, false, true><<<NB, 256, 0, stream>>>(tx0, A, B, Ws[l], bs[l], C,
                                                      stats, stats + 64, N);
    k_bncoef<<<1, 64, 0, stream>>>(stats, stats + 64, gs[l], bes[l], stats + 128, stats + 192, N);
    k_bnapply<<<DIV_UP(N * 16, 256), 256, 0, stream>>>(C, stats + 128, stats + 192, Dh, N * 16);
    tx0 = Dh;
  }
  // shortcut: Dh += x @ w_sc + b_sc
  k_gemm_v3<1, true, false><<<NB, 256, 0, stream>>>(x, nullptr, nullptr, w_sc, b_sc, Dh,
                                                    nullptr, nullptr, N);

  k_poolinit<<<DIV_UP(G * 64, 256), 256, 0, stream>>>(pooled, G * 64);
  k_pool<<<DIV_UP(N, 64), 256, 0, stream>>>(Dh, batch, pooled, N);
  k_final<<<G, 64, 0, stream>>>(pooled, w_lin, b_lin, (float*)d_out);
}

// Round 4
// 1483.030 us; speedup vs baseline: 1.9400x; 1.9400x over previous
//
#include <hip/hip_runtime.h>

#define DIV_UP(a,b) (((a)+(b)-1)/(b))

// ---------- ordered-uint float max keys ----------
__device__ __forceinline__ unsigned f2key(float f) {
  unsigned u = __float_as_uint(f);
  return (u & 0x80000000u) ? ~u : (u | 0x80000000u);
}
__device__ __forceinline__ float key2f(unsigned u) {
  unsigned b = (u & 0x80000000u) ? (u ^ 0x80000000u) : ~u;
  return __uint_as_float(b);
}

// ---------- utility ----------
__global__ void k_zero(int* p, int n) {
  int i = blockIdx.x * blockDim.x + threadIdx.x;
  if (i < n) p[i] = 0;
}

// ---------- degree count ----------
__global__ void k_count(const int* __restrict__ row, int* __restrict__ cnt, int E) {
  int e = blockIdx.x * blockDim.x + threadIdx.x;
  if (e < E) atomicAdd(&cnt[row[e]], 1);
}

__global__ void k_dis(const int* __restrict__ cnt, float* __restrict__ dis, int N) {
  int i = blockIdx.x * blockDim.x + threadIdx.x;
  if (i < N) {
    int c = cnt[i];
    dis[i] = (c > 0) ? rsqrtf((float)c) : 0.0f;
  }
}

// ---------- 3-kernel exclusive scan over cnt -> rowptr ----------
__global__ void k_scan1(const int* __restrict__ cnt, int* __restrict__ incl,
                        int* __restrict__ bsum, int N) {
  __shared__ int s[1024];
  int t = threadIdx.x;
  int i = blockIdx.x * 1024 + t;
  int v = (i < N) ? cnt[i] : 0;
  s[t] = v;
  __syncthreads();
  for (int off = 1; off < 1024; off <<= 1) {
    int add = (t >= off) ? s[t - off] : 0;
    __syncthreads();
    s[t] += add;
    __syncthreads();
  }
  if (i < N) incl[i] = s[t];
  if (t == 1023) bsum[blockIdx.x] = s[1023];
}

__global__ void k_scan2(const int* __restrict__ bsum, int* __restrict__ bex, int nb) {
  if (threadIdx.x == 0) {
    int run = 0;
    for (int b = 0; b < nb; ++b) { bex[b] = run; run += bsum[b]; }
  }
}

__global__ void k_scan3(const int* __restrict__ incl, const int* __restrict__ cnt,
                        const int* __restrict__ bex, int* __restrict__ rowptr,
                        int* __restrict__ cursor, int N, int E) {
  int i = blockIdx.x * blockDim.x + threadIdx.x;
  if (i < N) {
    int v = incl[i] - cnt[i] + bex[i >> 10];
    rowptr[i] = v;
    cursor[i] = v;
  }
  if (i == 0) rowptr[N] = E;
}

// ---------- CSR fill ----------
__global__ void k_fill(const int* __restrict__ row, const int* __restrict__ col,
                       const float* __restrict__ dis, int* __restrict__ cursor,
                       int* __restrict__ csr_col, float* __restrict__ csr_w, int E) {
  int e = blockIdx.x * blockDim.x + threadIdx.x;
  if (e >= E) return;
  int r = row[e], c = col[e];
  int idx = atomicAdd(&cursor[r], 1);
  csr_col[idx] = c;
  csr_w[idx] = -dis[r] * dis[c];
}

// ---------- prop: one wave per row, lane = feature, 8-wide MLP ----------
template <bool CHEB2>
__global__ __launch_bounds__(256) void k_prop(const int* __restrict__ rowptr,
                                              const int* __restrict__ csr_col,
                                              const float* __restrict__ csr_w,
                                              const float* __restrict__ z,
                                              const float* __restrict__ tx0,
                                              float* __restrict__ out, int N) {
  int n = blockIdx.x * 4 + (threadIdx.x >> 6);
  int lane = threadIdx.x & 63;
  if (n >= N) return;
  int beg = rowptr[n], end = rowptr[n + 1];
  float acc = 0.0f;
  for (int j = beg; j < end; j += 8) {
    int cc[8];
    float ww[8];
#pragma unroll
    for (int u = 0; u < 8; ++u) {
      int jj = j + u;
      bool ok = jj < end;          // wave-uniform
      cc[u] = ok ? csr_col[jj] : 0;
      ww[u] = ok ? csr_w[jj] : 0.0f;
    }
    float vv[8];
#pragma unroll
    for (int u = 0; u < 8; ++u) vv[u] = z[(size_t)cc[u] * 64 + lane];
#pragma unroll
    for (int u = 0; u < 8; ++u) acc = fmaf(ww[u], vv[u], acc);
  }
  if (CHEB2)
    out[(size_t)n * 64 + lane] = 2.0f * acc - tx0[(size_t)n * 64 + lane];
  else
    out[(size_t)n * 64 + lane] = acc;
}

// ---------- GEMM v4: lane = output column h, wave blocks 16 rows ----------
// Block = 256 thr = 4 waves; wave w handles row-group g = bid*4+w (16 rows).
// x loads: wave-uniform float4 (1 cacheline/instr). W column w_s[d*64+lane]:
// conflict-free, pairs into ds_read2_b32, reused across 16 rows -> 64 FMA
// per 2 LDS instrs. Stores coalesced. BN stats are lane-local sums.
template <int KK, bool ACC, bool STATS>
__global__ __launch_bounds__(256, 3) void k_gemm_v4(const float* __restrict__ t0,
                                                    const float* __restrict__ t1,
                                                    const float* __restrict__ t2,
                                                    const float* __restrict__ W,
                                                    const float* __restrict__ bias,
                                                    float* __restrict__ out,
                                                    float* __restrict__ sums,
                                                    float* __restrict__ sumsq, int N) {
  __shared__ float w_s[KK * 64 * 64];
  __shared__ float red[2][4][64];
  for (int i = threadIdx.x * 4; i < KK * 4096; i += 1024)
    *(float4*)&w_s[i] = *(const float4*)&W[i];
  __syncthreads();

  int lane = threadIdx.x & 63;
  int wid = threadIdx.x >> 6;
  int g = blockIdx.x * 4 + wid;
  int row0 = g * 16;
  bool active = row0 < N;
  bool full = (row0 + 16) <= N;
  const float* ts[3] = {t0, t1, t2};

  float acc[16];
  float bv = bias[lane];
#pragma unroll
  for (int r = 0; r < 16; ++r) acc[r] = bv;

  if (active) {
#pragma unroll
    for (int k = 0; k < KK; ++k) {
      const float* bp = ts[k] + (size_t)row0 * 64;
      for (int d4 = 0; d4 < 16; ++d4) {
        float4 xv[16];
        if (full) {
#pragma unroll
          for (int r = 0; r < 16; ++r)
            xv[r] = *(const float4*)(bp + r * 64 + d4 * 4);  // wave-uniform addr
        } else {
#pragma unroll
          for (int r = 0; r < 16; ++r)
            xv[r] = (row0 + r < N) ? *(const float4*)(bp + r * 64 + d4 * 4)
                                   : make_float4(0.f, 0.f, 0.f, 0.f);
        }
        int db = (k * 64 + d4 * 4) * 64 + lane;
        float w0 = w_s[db];
        float w1 = w_s[db + 64];
        float w2 = w_s[db + 128];
        float w3 = w_s[db + 192];
#pragma unroll
        for (int r = 0; r < 16; ++r) {
          float a = acc[r];
          a = fmaf(xv[r].x, w0, a);
          a = fmaf(xv[r].y, w1, a);
          a = fmaf(xv[r].z, w2, a);
          a = fmaf(xv[r].w, w3, a);
          acc[r] = a;
        }
      }
    }
  }

  if (STATS) {
    float s = 0.f, s2 = 0.f;
    if (active) {
#pragma unroll
      for (int r = 0; r < 16; ++r) {
        float v = (full || row0 + r < N) ? acc[r] : 0.f;
        s += v;
        s2 = fmaf(v, v, s2);
      }
    }
    red[0][wid][lane] = s;
    red[1][wid][lane] = s2;
    __syncthreads();
    if (wid == 0) {
      float a = red[0][0][lane] + red[0][1][lane] + red[0][2][lane] + red[0][3][lane];
      float b = red[1][0][lane] + red[1][1][lane] + red[1][2][lane] + red[1][3][lane];
      atomicAdd(&sums[lane], a);
      atomicAdd(&sumsq[lane], b);
    }
  }

  if (active) {
    float* op = out + (size_t)row0 * 64 + lane;
    if (full) {
#pragma unroll
      for (int r = 0; r < 16; ++r) {
        if (ACC)
          op[r * 64] += acc[r];
        else
          op[r * 64] = acc[r];
      }
    } else {
#pragma unroll
      for (int r = 0; r < 16; ++r) {
        if (row0 + r < N) {
          if (ACC)
            op[r * 64] += acc[r];
          else
            op[r * 64] = acc[r];
        }
      }
    }
  }
}

__global__ void k_bncoef(const float* __restrict__ sums, const float* __restrict__ sumsq,
                         const float* __restrict__ g, const float* __restrict__ be,
                         float* __restrict__ scale, float* __restrict__ shift, int N) {
  int h = threadIdx.x;
  if (h >= 64) return;
  float inv_n = 1.0f / (float)N;
  float mu = sums[h] * inv_n;
  float var = sumsq[h] * inv_n - mu * mu;
  float sc = g[h] * rsqrtf(var + 1e-5f);
  scale[h] = sc;
  shift[h] = be[h] - mu * sc;
}

// ---------- BN apply + LeakyReLU (float4) ----------
__global__ void k_bnapply(const float* __restrict__ X, const float* __restrict__ scale,
                          const float* __restrict__ shift, float* __restrict__ Y,
                          int total4) {
  int i = blockIdx.x * blockDim.x + threadIdx.x;
  if (i >= total4) return;
  int h = (i * 4) & 63;
  float4 v = ((const float4*)X)[i];
  float a, b, c, d;
  a = v.x * scale[h + 0] + shift[h + 0];
  b = v.y * scale[h + 1] + shift[h + 1];
  c = v.z * scale[h + 2] + shift[h + 2];
  d = v.w * scale[h + 3] + shift[h + 3];
  v.x = (a > 0.0f) ? a : 0.01f * a;
  v.y = (b > 0.0f) ? b : 0.01f * b;
  v.z = (c > 0.0f) ? c : 0.01f * c;
  v.w = (d > 0.0f) ? d : 0.01f * d;
  ((float4*)Y)[i] = v;
}

// ---------- pooling ----------
__global__ void k_poolinit(unsigned* __restrict__ pooled, int n) {
  int i = blockIdx.x * blockDim.x + threadIdx.x;
  if (i < n) pooled[i] = 0x007FFFFFu;  // key(-inf)
}

__global__ void k_pool(const float* __restrict__ X, const int* __restrict__ batch,
                       unsigned* __restrict__ pooled, int N) {
  int t = threadIdx.x;
  int h = t & 63;
  int rsub = t >> 6;
  int base = blockIdx.x * 64;
  int cur_g = -1;
  unsigned best = 0;
  for (int i = 0; i < 16; ++i) {
    int n = base + rsub + 4 * i;
    if (n >= N) break;
    int g = batch[n];
    unsigned k = f2key(X[(size_t)n * 64 + h]);
    if (g != cur_g) {
      if (cur_g >= 0) atomicMax(&pooled[cur_g * 64 + h], best);
      cur_g = g;
      best = k;
    } else {
      best = max(best, k);
    }
  }
  if (cur_g >= 0) atomicMax(&pooled[cur_g * 64 + h], best);
}

__global__ void k_final(const unsigned* __restrict__ pooled, const float* __restrict__ w_lin,
                        const float* __restrict__ b_lin, float* __restrict__ out) {
  int g = blockIdx.x;
  int h = threadIdx.x;
  float v = key2f(pooled[g * 64 + h]) * w_lin[h];
  for (int off = 32; off > 0; off >>= 1) v += __shfl_down(v, off, 64);
  if (h == 0) out[g] = v + b_lin[0];
}

extern "C" void kernel_launch(void* const* d_in, const int* in_sizes, int n_in,
                              void* d_out, int out_size, void* d_ws, size_t ws_size,
                              hipStream_t stream) {
  const float* x = (const float*)d_in[0];
  const int* ei = (const int*)d_in[1];
  const int* batch = (const int*)d_in[2];
  const float* w1 = (const float*)d_in[3];
  const float* b1 = (const float*)d_in[4];
  const float* w2 = (const float*)d_in[5];
  const float* b2 = (const float*)d_in[6];
  const float* w3 = (const float*)d_in[7];
  const float* b3 = (const float*)d_in[8];
  const float* g1 = (const float*)d_in[9];
  const float* be1 = (const float*)d_in[10];
  const float* g2 = (const float*)d_in[11];
  const float* be2 = (const float*)d_in[12];
  const float* g3 = (const float*)d_in[13];
  const float* be3 = (const float*)d_in[14];
  const float* w_sc = (const float*)d_in[15];
  const float* b_sc = (const float*)d_in[16];
  const float* w_lin = (const float*)d_in[17];
  const float* b_lin = (const float*)d_in[18];

  int N = in_sizes[0] / 64;
  int E = in_sizes[1] / 2;
  int G = out_size;
  const int* row = ei;
  const int* col = ei + E;

  char* p = (char*)d_ws;
  auto carve = [&](size_t bytes) -> void* {
    void* r = (void*)p;
    p += (bytes + 255) & ~(size_t)255;
    return r;
  };
  int* cnt = (int*)carve((size_t)N * 4);
  float* dis = (float*)carve((size_t)N * 4);
  int* rowptr = (int*)carve((size_t)(N + 1) * 4);
  int* cursor = (int*)carve((size_t)N * 4);
  int* incl = (int*)carve((size_t)N * 4);
  int* bsum = (int*)carve(1024);
  int* bex = (int*)carve(1024);
  int* csr_col = (int*)carve((size_t)E * 4);
  float* csr_w = (float*)carve((size_t)E * 4);
  float* A = (float*)carve((size_t)N * 64 * 4);
  float* B = (float*)carve((size_t)N * 64 * 4);
  float* C = (float*)carve((size_t)N * 64 * 4);
  float* Dh = (float*)carve((size_t)N * 64 * 4);
  float* stats = (float*)carve(256 * 4);  // sums|sumsq|scale|shift
  unsigned* pooled = (unsigned*)carve((size_t)G * 64 * 4);

  // ---- graph structure ----
  k_zero<<<DIV_UP(N, 256), 256, 0, stream>>>(cnt, N);
  k_count<<<DIV_UP(E, 256), 256, 0, stream>>>(row, cnt, E);
  k_dis<<<DIV_UP(N, 256), 256, 0, stream>>>(cnt, dis, N);
  int nb = DIV_UP(N, 1024);
  k_scan1<<<nb, 1024, 0, stream>>>(cnt, incl, bsum, N);
  k_scan2<<<1, 64, 0, stream>>>(bsum, bex, nb);
  k_scan3<<<DIV_UP(N, 256), 256, 0, stream>>>(incl, cnt, bex, rowptr, cursor, N, E);
  k_fill<<<DIV_UP(E, 256), 256, 0, stream>>>(row, col, dis, cursor, csr_col, csr_w, E);

  const float* Ws[3] = {w1, w2, w3};
  const float* bs[3] = {b1, b2, b3};
  const float* gs[3] = {g1, g2, g3};
  const float* bes[3] = {be1, be2, be3};

  int NG = DIV_UP(N, 16);           // 16-row groups
  int NB = DIV_UP(NG, 4);           // 4 waves per block
  const float* tx0 = x;
  for (int l = 0; l < 3; ++l) {
    k_prop<false><<<DIV_UP(N, 4), 256, 0, stream>>>(rowptr, csr_col, csr_w, tx0, nullptr, A, N);
    k_prop<true><<<DIV_UP(N, 4), 256, 0, stream>>>(rowptr, csr_col, csr_w, A, tx0, B, N);
    k_zero<<<1, 256, 0, stream>>>((int*)stats, 128);
    k_gemm_v4<3, false, true><<<NB, 256, 0, stream>>>(tx0, A, B, Ws[l], bs[l], C,
                                                      stats, stats + 64, N);
    k_bncoef<<<1, 64, 0, stream>>>(stats, stats + 64, gs[l], bes[l], stats + 128, stats + 192, N);
    k_bnapply<<<DIV_UP(N * 16, 256), 256, 0, stream>>>(C, stats + 128, stats + 192, Dh, N * 16);
    tx0 = Dh;
  }
  // shortcut: Dh += x @ w_sc + b_sc
  k_gemm_v4<1, true, false><<<NB, 256, 0, stream>>>(x, nullptr, nullptr, w_sc, b_sc, Dh,
                                                    nullptr, nullptr, N);

  k_poolinit<<<DIV_UP(G * 64, 256), 256, 0, stream>>>(pooled, G * 64);
  k_pool<<<DIV_UP(N, 64), 256, 0, stream>>>(Dh, batch, pooled, N);
  k_final<<<G, 64, 0, stream>>>(pooled, w_lin, b_lin, (float*)d_out);
}

// Round 5
// 1389.898 us; speedup vs baseline: 2.0700x; 1.0670x over previous
//
#include <hip/hip_runtime.h>

#define DIV_UP(a,b) (((a)+(b)-1)/(b))

// ---------- ordered-uint float max keys ----------
__device__ __forceinline__ unsigned f2key(float f) {
  unsigned u = __float_as_uint(f);
  return (u & 0x80000000u) ? ~u : (u | 0x80000000u);
}
__device__ __forceinline__ float key2f(unsigned u) {
  unsigned b = (u & 0x80000000u) ? (u ^ 0x80000000u) : ~u;
  return __uint_as_float(b);
}

// ---------- utility ----------
__global__ void k_zero(int* p, int n) {
  int i = blockIdx.x * blockDim.x + threadIdx.x;
  if (i < n) p[i] = 0;
}

// ---------- degree count ----------
__global__ void k_count(const int* __restrict__ row, int* __restrict__ cnt, int E) {
  int e = blockIdx.x * blockDim.x + threadIdx.x;
  if (e < E) atomicAdd(&cnt[row[e]], 1);
}

__global__ void k_dis(const int* __restrict__ cnt, float* __restrict__ dis, int N) {
  int i = blockIdx.x * blockDim.x + threadIdx.x;
  if (i < N) {
    int c = cnt[i];
    dis[i] = (c > 0) ? rsqrtf((float)c) : 0.0f;
  }
}

// ---------- 3-kernel exclusive scan over cnt -> rowptr ----------
__global__ void k_scan1(const int* __restrict__ cnt, int* __restrict__ incl,
                        int* __restrict__ bsum, int N) {
  __shared__ int s[1024];
  int t = threadIdx.x;
  int i = blockIdx.x * 1024 + t;
  int v = (i < N) ? cnt[i] : 0;
  s[t] = v;
  __syncthreads();
  for (int off = 1; off < 1024; off <<= 1) {
    int add = (t >= off) ? s[t - off] : 0;
    __syncthreads();
    s[t] += add;
    __syncthreads();
  }
  if (i < N) incl[i] = s[t];
  if (t == 1023) bsum[blockIdx.x] = s[1023];
}

__global__ void k_scan2(const int* __restrict__ bsum, int* __restrict__ bex, int nb) {
  if (threadIdx.x == 0) {
    int run = 0;
    for (int b = 0; b < nb; ++b) { bex[b] = run; run += bsum[b]; }
  }
}

__global__ void k_scan3(const int* __restrict__ incl, const int* __restrict__ cnt,
                        const int* __restrict__ bex, int* __restrict__ rowptr,
                        int* __restrict__ cursor, int N, int E) {
  int i = blockIdx.x * blockDim.x + threadIdx.x;
  if (i < N) {
    int v = incl[i] - cnt[i] + bex[i >> 10];
    rowptr[i] = v;
    cursor[i] = v;
  }
  if (i == 0) rowptr[N] = E;
}

// ---------- CSR fill ----------
__global__ void k_fill(const int* __restrict__ row, const int* __restrict__ col,
                       const float* __restrict__ dis, int* __restrict__ cursor,
                       int* __restrict__ csr_col, float* __restrict__ csr_w, int E) {
  int e = blockIdx.x * blockDim.x + threadIdx.x;
  if (e >= E) return;
  int r = row[e], c = col[e];
  int idx = atomicAdd(&cursor[r], 1);
  csr_col[idx] = c;
  csr_w[idx] = -dis[r] * dis[c];
}

// ---------- prop: wave per row, lane = feature, 8-wide MLP, fused epilogue ----
// MODE 1: out[n] = inA[n] + 2*acc          (V = Y1 + 2*P*Y2)
// MODE 2: out[n] = inA[n] - inB[n] + acc   (C = Y0 - Y2 + P*V)
template <int MODE>
__global__ __launch_bounds__(256) void k_prop2(const int* __restrict__ rowptr,
                                               const int* __restrict__ csr_col,
                                               const float* __restrict__ csr_w,
                                               const float* __restrict__ zsrc,
                                               const float* __restrict__ inA,
                                               const float* __restrict__ inB,
                                               float* __restrict__ out, int N) {
  int n = blockIdx.x * 4 + (threadIdx.x >> 6);
  int lane = threadIdx.x & 63;
  if (n >= N) return;
  int beg = rowptr[n], end = rowptr[n + 1];
  float acc = 0.0f;
  for (int j = beg; j < end; j += 8) {
    int cc[8];
    float ww[8];
#pragma unroll
    for (int u = 0; u < 8; ++u) {
      int jj = j + u;
      bool ok = jj < end;  // wave-uniform
      cc[u] = ok ? csr_col[jj] : 0;
      ww[u] = ok ? csr_w[jj] : 0.0f;
    }
    float vv[8];
#pragma unroll
    for (int u = 0; u < 8; ++u) vv[u] = zsrc[(size_t)cc[u] * 64 + lane];
#pragma unroll
    for (int u = 0; u < 8; ++u) acc = fmaf(ww[u], vv[u], acc);
  }
  size_t o = (size_t)n * 64 + lane;
  if (MODE == 1)
    out[o] = inA[o] + 2.0f * acc;
  else
    out[o] = inA[o] - inB[o] + acc;
}

// ---------- fused layer GEMM: Y[0|1|2] = X[N,64] @ W[k][64][64], bias on Y0 ---
// Block 256 = 4 waves; wave handles 16 rows x 192 cols (48 acc/lane).
// W staged to LDS as w_s[d*192 + k*64 + h] (conflict-free: bank = lane%32).
// x loads are wave-uniform float4 from global (1 line/instr, L1-shared).
// Per d4: 12 LDS b32 (~70 cyc) vs 192 FMA insts (budget 96 LDS-cyc) -> VALU-bound.
__global__ __launch_bounds__(256, 2) void k_gemm192(const float* __restrict__ X,
                                                    const float* __restrict__ W,
                                                    const float* __restrict__ bias,
                                                    float* __restrict__ Y0,
                                                    float* __restrict__ Y1,
                                                    float* __restrict__ Y2, int N) {
  __shared__ float w_s[64 * 192];
  for (int i4 = threadIdx.x; i4 < 3072; i4 += 256) {
    int k = i4 >> 10, rem = i4 & 1023;
    int d = rem >> 4, h4 = rem & 15;
    float4 v = ((const float4*)W)[i4];
    *(float4*)&w_s[d * 192 + k * 64 + h4 * 4] = v;
  }
  __syncthreads();

  int lane = threadIdx.x & 63;
  int wid = threadIdx.x >> 6;
  int rowbase = (blockIdx.x * 4 + wid) * 16;
  if (rowbase >= N) return;
  bool full = (rowbase + 16) <= N;

  float bv = bias[lane];
  float acc[48];
#pragma unroll
  for (int r = 0; r < 16; ++r) {
    acc[r * 3 + 0] = bv;
    acc[r * 3 + 1] = 0.f;
    acc[r * 3 + 2] = 0.f;
  }
  const float* xb = X + (size_t)rowbase * 64;

  if (full) {
    for (int d4 = 0; d4 < 16; ++d4) {
      float w[12];
#pragma unroll
      for (int j = 0; j < 3; ++j)
#pragma unroll
        for (int k = 0; k < 4; ++k)
          w[j * 4 + k] = w_s[(d4 * 4 + k) * 192 + j * 64 + lane];
#pragma unroll
      for (int r = 0; r < 16; ++r) {
        float4 xv = *(const float4*)(xb + r * 64 + d4 * 4);  // wave-uniform
#pragma unroll
        for (int j = 0; j < 3; ++j) {
          float a = acc[r * 3 + j];
          a = fmaf(xv.x, w[j * 4 + 0], a);
          a = fmaf(xv.y, w[j * 4 + 1], a);
          a = fmaf(xv.z, w[j * 4 + 2], a);
          a = fmaf(xv.w, w[j * 4 + 3], a);
          acc[r * 3 + j] = a;
        }
      }
    }
  } else {
    for (int d4 = 0; d4 < 16; ++d4) {
      float w[12];
#pragma unroll
      for (int j = 0; j < 3; ++j)
#pragma unroll
        for (int k = 0; k < 4; ++k)
          w[j * 4 + k] = w_s[(d4 * 4 + k) * 192 + j * 64 + lane];
#pragma unroll
      for (int r = 0; r < 16; ++r) {
        float4 xv = (rowbase + r < N) ? *(const float4*)(xb + r * 64 + d4 * 4)
                                      : make_float4(0.f, 0.f, 0.f, 0.f);
#pragma unroll
        for (int j = 0; j < 3; ++j) {
          float a = acc[r * 3 + j];
          a = fmaf(xv.x, w[j * 4 + 0], a);
          a = fmaf(xv.y, w[j * 4 + 1], a);
          a = fmaf(xv.z, w[j * 4 + 2], a);
          a = fmaf(xv.w, w[j * 4 + 3], a);
          acc[r * 3 + j] = a;
        }
      }
    }
  }

#pragma unroll
  for (int r = 0; r < 16; ++r) {
    int row = rowbase + r;
    if (full || row < N) {
      size_t o = (size_t)row * 64 + lane;
      Y0[o] = acc[r * 3 + 0];
      Y1[o] = acc[r * 3 + 1];
      Y2[o] = acc[r * 3 + 2];
    }
  }
}

// ---------- shortcut GEMM: out[n] += bias + X[n] @ W[64][64] ----------
__global__ __launch_bounds__(256, 2) void k_gemmsc(const float* __restrict__ X,
                                                   const float* __restrict__ W,
                                                   const float* __restrict__ bias,
                                                   float* __restrict__ out, int N) {
  __shared__ float w_s[64 * 64];
  for (int i4 = threadIdx.x; i4 < 1024; i4 += 256)
    *(float4*)&w_s[i4 * 4] = ((const float4*)W)[i4];
  __syncthreads();

  int lane = threadIdx.x & 63;
  int wid = threadIdx.x >> 6;
  int rowbase = (blockIdx.x * 4 + wid) * 16;
  if (rowbase >= N) return;
  bool full = (rowbase + 16) <= N;

  float acc[16];
  float bv = bias[lane];
#pragma unroll
  for (int r = 0; r < 16; ++r) acc[r] = bv;
  const float* xb = X + (size_t)rowbase * 64;

  for (int d4 = 0; d4 < 16; ++d4) {
    float w0 = w_s[(d4 * 4 + 0) * 64 + lane];
    float w1 = w_s[(d4 * 4 + 1) * 64 + lane];
    float w2 = w_s[(d4 * 4 + 2) * 64 + lane];
    float w3 = w_s[(d4 * 4 + 3) * 64 + lane];
#pragma unroll
    for (int r = 0; r < 16; ++r) {
      float4 xv;
      if (full || rowbase + r < N)
        xv = *(const float4*)(xb + r * 64 + d4 * 4);
      else
        xv = make_float4(0.f, 0.f, 0.f, 0.f);
      float a = acc[r];
      a = fmaf(xv.x, w0, a);
      a = fmaf(xv.y, w1, a);
      a = fmaf(xv.z, w2, a);
      a = fmaf(xv.w, w3, a);
      acc[r] = a;
    }
  }

#pragma unroll
  for (int r = 0; r < 16; ++r) {
    int row = rowbase + r;
    if (full || row < N) {
      size_t o = (size_t)row * 64 + lane;
      out[o] += acc[r];
    }
  }
}

// ---------- BN stats: per-column sum / sumsq ----------
__global__ void k_bnstats(const float* __restrict__ X, float* __restrict__ sums,
                          float* __restrict__ sumsq, int N) {
  int lane = threadIdx.x & 63;
  int wid = threadIdx.x >> 6;
  float s = 0.0f, s2 = 0.0f;
  for (int n = blockIdx.x * 4 + wid; n < N; n += gridDim.x * 4) {
    float v = X[(size_t)n * 64 + lane];
    s += v;
    s2 = fmaf(v, v, s2);
  }
  __shared__ float ls[4][64], ls2[4][64];
  ls[wid][lane] = s;
  ls2[wid][lane] = s2;
  __syncthreads();
  if (threadIdx.x < 64) {
    float a = ls[0][lane] + ls[1][lane] + ls[2][lane] + ls[3][lane];
    float b = ls2[0][lane] + ls2[1][lane] + ls2[2][lane] + ls2[3][lane];
    atomicAdd(&sums[lane], a);
    atomicAdd(&sumsq[lane], b);
  }
}

__global__ void k_bncoef(const float* __restrict__ sums, const float* __restrict__ sumsq,
                         const float* __restrict__ g, const float* __restrict__ be,
                         float* __restrict__ scale, float* __restrict__ shift, int N) {
  int h = threadIdx.x;
  if (h >= 64) return;
  float inv_n = 1.0f / (float)N;
  float mu = sums[h] * inv_n;
  float var = sumsq[h] * inv_n - mu * mu;
  float sc = g[h] * rsqrtf(var + 1e-5f);
  scale[h] = sc;
  shift[h] = be[h] - mu * sc;
}

// ---------- BN apply + LeakyReLU (float4) ----------
__global__ void k_bnapply(const float* __restrict__ X, const float* __restrict__ scale,
                          const float* __restrict__ shift, float* __restrict__ Y,
                          int total4) {
  int i = blockIdx.x * blockDim.x + threadIdx.x;
  if (i >= total4) return;
  int h = (i * 4) & 63;
  float4 v = ((const float4*)X)[i];
  float a, b, c, d;
  a = v.x * scale[h + 0] + shift[h + 0];
  b = v.y * scale[h + 1] + shift[h + 1];
  c = v.z * scale[h + 2] + shift[h + 2];
  d = v.w * scale[h + 3] + shift[h + 3];
  v.x = (a > 0.0f) ? a : 0.01f * a;
  v.y = (b > 0.0f) ? b : 0.01f * b;
  v.z = (c > 0.0f) ? c : 0.01f * c;
  v.w = (d > 0.0f) ? d : 0.01f * d;
  ((float4*)Y)[i] = v;
}

// ---------- pooling ----------
__global__ void k_poolinit(unsigned* __restrict__ pooled, int n) {
  int i = blockIdx.x * blockDim.x + threadIdx.x;
  if (i < n) pooled[i] = 0x007FFFFFu;  // key(-inf)
}

__global__ void k_pool(const float* __restrict__ X, const int* __restrict__ batch,
                       unsigned* __restrict__ pooled, int N) {
  int t = threadIdx.x;
  int h = t & 63;
  int rsub = t >> 6;
  int base = blockIdx.x * 64;
  int cur_g = -1;
  unsigned best = 0;
  for (int i = 0; i < 16; ++i) {
    int n = base + rsub + 4 * i;
    if (n >= N) break;
    int g = batch[n];
    unsigned k = f2key(X[(size_t)n * 64 + h]);
    if (g != cur_g) {
      if (cur_g >= 0) atomicMax(&pooled[cur_g * 64 + h], best);
      cur_g = g;
      best = k;
    } else {
      best = max(best, k);
    }
  }
  if (cur_g >= 0) atomicMax(&pooled[cur_g * 64 + h], best);
}

__global__ void k_final(const unsigned* __restrict__ pooled, const float* __restrict__ w_lin,
                        const float* __restrict__ b_lin, float* __restrict__ out) {
  int g = blockIdx.x;
  int h = threadIdx.x;
  float v = key2f(pooled[g * 64 + h]) * w_lin[h];
  for (int off = 32; off > 0; off >>= 1) v += __shfl_down(v, off, 64);
  if (h == 0) out[g] = v + b_lin[0];
}

extern "C" void kernel_launch(void* const* d_in, const int* in_sizes, int n_in,
                              void* d_out, int out_size, void* d_ws, size_t ws_size,
                              hipStream_t stream) {
  const float* x = (const float*)d_in[0];
  const int* ei = (const int*)d_in[1];
  const int* batch = (const int*)d_in[2];
  const float* w1 = (const float*)d_in[3];
  const float* b1 = (const float*)d_in[4];
  const float* w2 = (const float*)d_in[5];
  const float* b2 = (const float*)d_in[6];
  const float* w3 = (const float*)d_in[7];
  const float* b3 = (const float*)d_in[8];
  const float* g1 = (const float*)d_in[9];
  const float* be1 = (const float*)d_in[10];
  const float* g2 = (const float*)d_in[11];
  const float* be2 = (const float*)d_in[12];
  const float* g3 = (const float*)d_in[13];
  const float* be3 = (const float*)d_in[14];
  const float* w_sc = (const float*)d_in[15];
  const float* b_sc = (const float*)d_in[16];
  const float* w_lin = (const float*)d_in[17];
  const float* b_lin = (const float*)d_in[18];

  int N = in_sizes[0] / 64;
  int E = in_sizes[1] / 2;
  int G = out_size;
  const int* row = ei;
  const int* col = ei + E;

  char* p = (char*)d_ws;
  auto carve = [&](size_t bytes) -> void* {
    void* r = (void*)p;
    p += (bytes + 255) & ~(size_t)255;
    return r;
  };
  int* cnt = (int*)carve((size_t)N * 4);
  float* dis = (float*)carve((size_t)N * 4);
  int* rowptr = (int*)carve((size_t)(N + 1) * 4);
  int* cursor = (int*)carve((size_t)N * 4);
  int* incl = (int*)carve((size_t)N * 4);
  int* bsum = (int*)carve(1024);
  int* bex = (int*)carve(1024);
  int* csr_col = (int*)carve((size_t)E * 4);
  float* csr_w = (float*)carve((size_t)E * 4);
  float* Y0 = (float*)carve((size_t)N * 64 * 4);
  float* Y1 = (float*)carve((size_t)N * 64 * 4);
  float* Y2 = (float*)carve((size_t)N * 64 * 4);
  float* P = (float*)carve((size_t)N * 64 * 4);
  float* stats = (float*)carve(256 * 4);  // sums|sumsq|scale|shift
  unsigned* pooled = (unsigned*)carve((size_t)G * 64 * 4);

  // ---- graph structure ----
  k_zero<<<DIV_UP(N, 256), 256, 0, stream>>>(cnt, N);
  k_count<<<DIV_UP(E, 256), 256, 0, stream>>>(row, cnt, E);
  k_dis<<<DIV_UP(N, 256), 256, 0, stream>>>(cnt, dis, N);
  int nb = DIV_UP(N, 1024);
  k_scan1<<<nb, 1024, 0, stream>>>(cnt, incl, bsum, N);
  k_scan2<<<1, 64, 0, stream>>>(bsum, bex, nb);
  k_scan3<<<DIV_UP(N, 256), 256, 0, stream>>>(incl, cnt, bex, rowptr, cursor, N, E);
  k_fill<<<DIV_UP(E, 256), 256, 0, stream>>>(row, col, dis, cursor, csr_col, csr_w, E);

  const float* Ws[3] = {w1, w2, w3};
  const float* bs[3] = {b1, b2, b3};
  const float* gs[3] = {g1, g2, g3};
  const float* bes[3] = {be1, be2, be3};

  int NBG = DIV_UP(N, 64);   // gemm blocks (4 waves x 16 rows)
  int NBP = DIV_UP(N, 4);    // prop blocks (4 waves x 1 row)
  const float* XIN = x;
  for (int l = 0; l < 3; ++l) {
    // Y0|Y1|Y2 = XIN @ [W0|W1|W2], bias on Y0
    k_gemm192<<<NBG, 256, 0, stream>>>(XIN, Ws[l], bs[l], Y0, Y1, Y2, N);
    // V (into Y1) = Y1 + 2*P*Y2
    k_prop2<1><<<NBP, 256, 0, stream>>>(rowptr, csr_col, csr_w, Y2, Y1, nullptr, Y1, N);
    // C (into Y2) = Y0 - Y2 + P*V
    k_prop2<2><<<NBP, 256, 0, stream>>>(rowptr, csr_col, csr_w, Y1, Y0, Y2, Y2, N);
    // BN + LeakyReLU
    k_zero<<<1, 256, 0, stream>>>((int*)stats, 128);
    k_bnstats<<<1024, 256, 0, stream>>>(Y2, stats, stats + 64, N);
    k_bncoef<<<1, 64, 0, stream>>>(stats, stats + 64, gs[l], bes[l], stats + 128, stats + 192, N);
    k_bnapply<<<DIV_UP(N * 16, 256), 256, 0, stream>>>(Y2, stats + 128, stats + 192, P, N * 16);
    XIN = P;
  }
  // shortcut: P += x @ w_sc + b_sc
  k_gemmsc<<<NBG, 256, 0, stream>>>(x, w_sc, b_sc, P, N);

  k_poolinit<<<DIV_UP(G * 64, 256), 256, 0, stream>>>(pooled, G * 64);
  k_pool<<<DIV_UP(N, 64), 256, 0, stream>>>(P, batch, pooled, N);
  k_final<<<G, 64, 0, stream>>>(pooled, w_lin, b_lin, (float*)d_out);
}